// Round 16
// baseline (94.144 us; speedup 1.0000x reference)
//
#include <hip/hip_runtime.h>
#include <cstdint>

// Ball query: B=8, N=4096, radius=0.2, nsample=32. Queries == sources.
// Output int32 (B,N,32): first 32 in-radius indices ascending, padded with
// the first match.
//
// NUMERICS (LOCKED, R8-verified absmax=0): expansion form f32,
//   sq  = (x*x + y*y) + z*z              -- plain, no FMA
//   dot = fma(qz,sz, fma(qy,sy, qx*sx))  -- FMA, K ascending
//   d2  = (sqq + sqs) - (dot + dot)
//   match = d2 < 0.04f
// Inline asm (immune to -ffast-math). DO NOT CHANGE the op sequence.
//
// R16: R15 proved wall ~= max-over-blocks(longest wave in block): within-
// block sorting gave EVERY block a long wave (regression). This round:
// GLOBAL counting-sort of each batch's 4096 queries by analytic scan-length
// proxy (kernel 1, perf-only), then wave w of block i takes 8 consecutive
// ranks from stripe G = w*64+i: waves homogeneous (work ~= sum of means),
// blocks get one wave per length-octile (durations equalized). Branch-free
// 8-query rounds (R14's 67%-VALUBusy structure), 256-pt uniform exit.

#define BQ_N   4096
#define BQ_B   8
#define BQ_NS  32
#define BQ_R2  0.04f

__device__ __forceinline__ float sq_plain(float x, float y, float z) {
    float r, t;
    asm("v_mul_f32 %0, %2, %2\n\t"
        "v_mul_f32 %1, %3, %3\n\t"
        "v_add_f32 %0, %0, %1\n\t"
        "v_mul_f32 %1, %4, %4\n\t"
        "v_add_f32 %0, %0, %1"
        : "=&v"(r), "=&v"(t)
        : "v"(x), "v"(y), "v"(z));
    return r;
}

// Query operands in SGPRs (wave-uniform; 1 SGPR read per VALU op -- legal).
__device__ __forceinline__ float d2_mixed_s(float qx, float qy, float qz,
                                            float sqq,
                                            float sx, float sy, float sz,
                                            float sqs) {
    float r, t;
    asm("v_mul_f32 %0, %2, %5\n\t"     // qx*sx
        "v_fma_f32 %0, %3, %6, %0\n\t" // + qy*sy (fused)
        "v_fma_f32 %0, %4, %7, %0\n\t" // + qz*sz (fused) = dot
        "v_add_f32 %0, %0, %0\n\t"     // 2*dot (exact)
        "v_add_f32 %1, %8, %9\n\t"     // sqq + sqs
        "v_sub_f32 %0, %1, %0"         // d2
        : "=&v"(r), "=&v"(t)
        : "s"(qx), "s"(qy), "s"(qz), "v"(sx), "v"(sy), "v"(sz),
          "s"(sqq), "v"(sqs));
    return r;
}

__device__ __forceinline__ float rfl(float v) {
    return __int_as_float(__builtin_amdgcn_readfirstlane(__float_as_int(v)));
}

// 1D r-ball/[0,1] overlap fraction along one axis -- density proxy, perf-only.
__device__ __forceinline__ float gfun(float q) {
    float t = fminf(q, 1.0f - q) * 5.0f;
    t = fminf(t, 1.0f);
    return 0.5f + (0.75f - 0.25f * t * t) * t;
}

// ---------- kernel 1: per-batch counting sort by density proxy ----------
__global__ __launch_bounds__(512)
void bq_sort_kernel(const float* __restrict__ xyz, int* __restrict__ perm)
{
    __shared__ int hist[256];
    __shared__ int scanbuf[256];
    const int b = blockIdx.x;                      // one block per batch
    const float* __restrict__ src = xyz + (size_t)b * BQ_N * 3;
    int* __restrict__ pb = perm + b * BQ_N;
    const int t = threadIdx.x;                     // 512 threads

    if (t < 256) hist[t] = 0;
    __syncthreads();

    int bins[8];
    #pragma unroll
    for (int i = 0; i < 8; ++i) {
        const int q = t + (i << 9);
        const float g3 = gfun(src[3 * q + 0]) * gfun(src[3 * q + 1]) *
                         gfun(src[3 * q + 2]);
        int bin = (int)(g3 * 255.99f);
        bin = bin < 0 ? 0 : (bin > 255 ? 255 : bin);
        bins[i] = bin;
        atomicAdd(&hist[bin], 1);
    }
    __syncthreads();

    // inclusive Hillis-Steele scan over 256 bins
    if (t < 256) scanbuf[t] = hist[t];
    __syncthreads();
    for (int off = 1; off < 256; off <<= 1) {
        int add = 0;
        if (t < 256 && t >= off) add = scanbuf[t - off];
        __syncthreads();
        if (t < 256) scanbuf[t] += add;
        __syncthreads();
    }
    // hist[b] <- exclusive base; then used as running rank counter
    if (t < 256) hist[t] = scanbuf[t] - hist[t];
    __syncthreads();

    #pragma unroll
    for (int i = 0; i < 8; ++i) {
        const int q = t + (i << 9);
        const int rank = atomicAdd(&hist[bins[i]], 1);
        pb[rank] = q;
    }
}

// ---------- emit machinery (validated R8-R15) ----------
__device__ __forceinline__ void emit_query(int* orow, int lane, uint64_t word) {
    const int cnt = __popcll(word);
    int incl = cnt;
    #pragma unroll
    for (int off = 1; off < 64; off <<= 1) {
        const int t = __shfl_up(incl, off);
        if (lane >= off) incl += t;
    }
    const int pre   = incl - cnt;
    const int total = __shfl(incl, 63);

    int first;
    const uint64_t nz = __ballot(word != 0ull);
    if (nz == 0ull) {
        first = BQ_N;   // defensive; self-match makes this unreachable
    } else {
        const int fl = __builtin_ctzll(nz);
        const uint64_t fw = __shfl(word, fl);
        first = (fl << 6) + __builtin_ctzll(fw);
    }

    uint64_t w = word;
    int pos = pre;
    while (w != 0ull && pos < BQ_NS) {
        const int bit = __builtin_ctzll(w);
        orow[pos] = (lane << 6) + bit;
        w &= (w - 1);
        ++pos;
    }
    if (lane >= total && lane < BQ_NS) orow[lane] = first;  // padding
}

// ---------- kernel 2: main scan ----------
__global__ __launch_bounds__(512, 4)
void ball_query_kernel(const float* __restrict__ xyz,
                       const int* __restrict__ perm,
                       int* __restrict__ out)
{
    __shared__ float4 pts[BQ_N];   // 64 KiB -> 2 blocks/CU, 16 waves/CU

    const int b  = blockIdx.x >> 6;        // 64 blocks per batch
    const int ib = blockIdx.x & 63;
    const float* __restrict__ src = xyz + (size_t)b * BQ_N * 3;
    const int* __restrict__ pb = perm + b * BQ_N;
    const int lane = threadIdx.x & 63;
    const int wid  = threadIdx.x >> 6;     // 0..7
    int* __restrict__ outb = out + (size_t)(b * BQ_N) * BQ_NS;

    // Stripe: wave w of block ib -> rank group G = w*64+ib (8 consecutive
    // ranks). Waves homogeneous; each block spans all length-octiles.
    const int G = (wid << 6) + ib;
    int qidx[8];
    float qx[8], qy[8], qz[8], qw[8];
    #pragma unroll
    for (int j = 0; j < 8; ++j) {
        const int m = pb[(G << 3) + j];    // wave-uniform
        qidx[j] = m;
        const float x = src[3 * m + 0];
        const float y = src[3 * m + 1];
        const float z = src[3 * m + 2];
        const float w = sq_plain(x, y, z);
        qx[j] = rfl(x); qy[j] = rfl(y); qz[j] = rfl(z); qw[j] = rfl(w);
    }

    for (int j = threadIdx.x; j < BQ_N; j += 512) {
        const float x = src[3 * j + 0];
        const float y = src[3 * j + 1];
        const float z = src[3 * j + 2];
        pts[j] = make_float4(x, y, z, sq_plain(x, y, z));
    }
    __syncthreads();

    uint64_t W[8] = {0, 0, 0, 0, 0, 0, 0, 0};
    int      F[8] = {0, 0, 0, 0, 0, 0, 0, 0};

    // Branch-free 8-query rounds; uniform all-done check per 256-pt chunk.
    #pragma unroll 1
    for (int c = 0; c < 16; ++c) {
        #pragma unroll
        for (int u = 0; u < 4; ++u) {
            const int k = (c << 2) + u;
            const float4 s = pts[(k << 6) + lane];
            #pragma unroll
            for (int j = 0; j < 8; ++j) {
                const float d2 = d2_mixed_s(qx[j], qy[j], qz[j], qw[j],
                                            s.x, s.y, s.z, s.w);
                const uint64_t bal = __ballot(d2 < BQ_R2);
                if (lane == k) W[j] = bal;
                F[j] += (int)__popcll(bal);
            }
        }
        bool done = true;
        #pragma unroll
        for (int j = 0; j < 8; ++j) done = done && (F[j] >= BQ_NS);
        if (done) break;   // wave-uniform
    }

    #pragma unroll 1
    for (int j = 0; j < 8; ++j)
        emit_query(outb + (size_t)qidx[j] * BQ_NS, lane, W[j]);
}

extern "C" void kernel_launch(void* const* d_in, const int* in_sizes, int n_in,
                              void* d_out, int out_size, void* d_ws, size_t ws_size,
                              hipStream_t stream)
{
    const float* xyz = (const float*)d_in[0];   // (8, 4096, 3) f32
    int* out  = (int*)d_out;                    // (8, 4096, 32) int32
    int* perm = (int*)d_ws;                     // 8*4096 ints = 128 KB scratch

    hipLaunchKernelGGL(bq_sort_kernel, dim3(BQ_B), dim3(512), 0, stream,
                       xyz, perm);
    hipLaunchKernelGGL(ball_query_kernel, dim3(BQ_B * 64), dim3(512), 0, stream,
                       xyz, perm, out);
}